// Round 5
// baseline (262.409 us; speedup 1.0000x reference)
//
#include <hip/hip_runtime.h>

// E8 lattice closest-point decode, TWO 8-float rows per thread (grid-stride).
// E8 = D8 ∪ (D8 + 1/2). Decode both cosets, keep the nearer (ties -> coset 0).
// Bit-exactness notes:
//  - jnp.round == round-half-to-even == rintf (v_rndne_f32)
//  - jnp.argmax: first index of max -> forward scan, strict '>'
//  - distance sums use numpy's pairwise tree order; FMA contraction disabled
//  - coset-1 residual computed as x - (f1 + 0.5), matching the reference
// Memory: read-once / write-once -> nontemporal hints keep L2/L3 clean.
// Note: nontemporal builtins need native vector types, not HIP_vector_type.

typedef float f32x4 __attribute__((ext_vector_type(4)));

__device__ __forceinline__ void e8_decode_row(const float xr[8], float o[8]) {
  #pragma clang fp contract(off)
  float c0[8], c1[8];

  // ---- coset 0: closest point of D8 to x ----
  {
    float f[8], d[8];
    float sum = 0.0f;
    float best = -1.0f, dworst = 0.0f;
    int worst = 0;
    #pragma unroll
    for (int i = 0; i < 8; ++i) {
      f[i] = rintf(xr[i]);
      d[i] = xr[i] - f[i];
      float ad = fabsf(d[i]);
      if (ad > best) { best = ad; worst = i; dworst = d[i]; }
      sum += f[i];
    }
    int odd = ((int)sum) & 1;
    float step = (dworst >= 0.0f) ? 1.0f : -1.0f;
    float adj = odd ? step : 0.0f;
    #pragma unroll
    for (int i = 0; i < 8; ++i) {
      c0[i] = (i == worst) ? (f[i] + adj) : f[i];
    }
  }

  // ---- coset 1: closest point of D8 to (x - 1/2), then + 1/2 ----
  {
    float f[8], d[8];
    float sum = 0.0f;
    float best = -1.0f, dworst = 0.0f;
    int worst = 0;
    #pragma unroll
    for (int i = 0; i < 8; ++i) {
      float y = xr[i] - 0.5f;
      f[i] = rintf(y);
      d[i] = y - f[i];
      float ad = fabsf(d[i]);
      if (ad > best) { best = ad; worst = i; dworst = d[i]; }
      sum += f[i];
    }
    int odd = ((int)sum) & 1;
    float step = (dworst >= 0.0f) ? 1.0f : -1.0f;
    float adj = odd ? step : 0.0f;
    #pragma unroll
    for (int i = 0; i < 8; ++i) {
      float fi = (i == worst) ? (f[i] + adj) : f[i];
      c1[i] = fi + 0.5f;   // exact: integer + 0.5 in fp32
    }
  }

  // ---- squared distances, numpy pairwise order, no FMA ----
  float q0[8], q1[8];
  #pragma unroll
  for (int i = 0; i < 8; ++i) {
    float r0 = xr[i] - c0[i];
    q0[i] = r0 * r0;
    float r1 = xr[i] - c1[i];
    q1[i] = r1 * r1;
  }
  float d0 = ((q0[0] + q0[1]) + (q0[2] + q0[3])) + ((q0[4] + q0[5]) + (q0[6] + q0[7]));
  float d1 = ((q1[0] + q1[1]) + (q1[2] + q1[3])) + ((q1[4] + q1[5]) + (q1[6] + q1[7]));

  bool pick0 = (d0 <= d1);
  #pragma unroll
  for (int i = 0; i < 8; ++i) {
    o[i] = pick0 ? c0[i] : c1[i];
  }
}

__global__ __launch_bounds__(256) void e8_decode_kernel(
    const float* __restrict__ x, float* __restrict__ out, int npairs, int nrows) {
  int stride = gridDim.x * blockDim.x;
  for (int p = blockIdx.x * blockDim.x + threadIdx.x; p < npairs; p += stride) {
    const f32x4* xv = reinterpret_cast<const f32x4*>(x) + (size_t)p * 4;
    f32x4 v0 = __builtin_nontemporal_load(xv + 0);
    f32x4 v1 = __builtin_nontemporal_load(xv + 1);
    f32x4 v2 = __builtin_nontemporal_load(xv + 2);
    f32x4 v3 = __builtin_nontemporal_load(xv + 3);

    float ra[8] = {v0.x, v0.y, v0.z, v0.w, v1.x, v1.y, v1.z, v1.w};
    float rb[8] = {v2.x, v2.y, v2.z, v2.w, v3.x, v3.y, v3.z, v3.w};
    float oa[8], ob[8];
    e8_decode_row(ra, oa);
    e8_decode_row(rb, ob);

    f32x4 w0 = {oa[0], oa[1], oa[2], oa[3]};
    f32x4 w1 = {oa[4], oa[5], oa[6], oa[7]};
    f32x4 w2 = {ob[0], ob[1], ob[2], ob[3]};
    f32x4 w3 = {ob[4], ob[5], ob[6], ob[7]};

    f32x4* ov = reinterpret_cast<f32x4*>(out) + (size_t)p * 4;
    __builtin_nontemporal_store(w0, ov + 0);
    __builtin_nontemporal_store(w1, ov + 1);
    __builtin_nontemporal_store(w2, ov + 2);
    __builtin_nontemporal_store(w3, ov + 3);
  }

  // tail: odd final row (not hit for 4M rows, kept for generality)
  if (nrows & 1) {
    int last = nrows - 1;
    if (blockIdx.x == 0 && threadIdx.x == 0) {
      const f32x4* xv = reinterpret_cast<const f32x4*>(x) + (size_t)last * 2;
      f32x4 a = xv[0];
      f32x4 b = xv[1];
      float r[8] = {a.x, a.y, a.z, a.w, b.x, b.y, b.z, b.w};
      float o[8];
      e8_decode_row(r, o);
      f32x4* ov = reinterpret_cast<f32x4*>(out) + (size_t)last * 2;
      f32x4 w0 = {o[0], o[1], o[2], o[3]};
      f32x4 w1 = {o[4], o[5], o[6], o[7]};
      ov[0] = w0;
      ov[1] = w1;
    }
  }
}

extern "C" void kernel_launch(void* const* d_in, const int* in_sizes, int n_in,
                              void* d_out, int out_size, void* d_ws, size_t ws_size,
                              hipStream_t stream) {
  const float* x = (const float*)d_in[0];
  float* out = (float*)d_out;
  int nrows = in_sizes[0] / 8;
  int npairs = nrows / 2;
  int block = 256;
  int grid = (npairs + block - 1) / block;
  if (grid > 2048) grid = 2048;   // 8192 waves = full residency; grid-stride covers rest
  e8_decode_kernel<<<grid, block, 0, stream>>>(x, out, npairs, nrows);
}

// Round 7
// 235.909 us; speedup vs baseline: 1.1123x; 1.1123x over previous
//
#include <hip/hip_runtime.h>

// E8 lattice closest-point decode, TWO 8-float rows per thread (grid-stride).
// E8 = D8 ∪ (D8 + 1/2). Decode both cosets, keep the nearer (ties -> coset 0).
// Bit-exactness notes:
//  - jnp.round == round-half-to-even == rintf (v_rndne_f32)
//  - jnp.argmax: first index of max -> forward scan, strict '>'
//  - distance sums use numpy's pairwise tree order; FMA contraction disabled
//  - coset-1 residual computed as x - (f1 + 0.5), matching the reference
// Memory: PLAIN float4 loads/stores. Round-5 lesson: nontemporal stores
// produced 1.5x WRITE_SIZE (partial-line HBM bursts, 192MB for a 128MB
// output) and dropped BW to 2.5 TB/s. L2 write-coalescing needs normal
// stores.

__device__ __forceinline__ void e8_decode_row(const float xr[8], float o[8]) {
  #pragma clang fp contract(off)
  float c0[8], c1[8];

  // ---- coset 0: closest point of D8 to x ----
  {
    float f[8], d[8];
    float sum = 0.0f;
    float best = -1.0f, dworst = 0.0f;
    int worst = 0;
    #pragma unroll
    for (int i = 0; i < 8; ++i) {
      f[i] = rintf(xr[i]);
      d[i] = xr[i] - f[i];
      float ad = fabsf(d[i]);
      if (ad > best) { best = ad; worst = i; dworst = d[i]; }
      sum += f[i];
    }
    int odd = ((int)sum) & 1;
    float step = (dworst >= 0.0f) ? 1.0f : -1.0f;
    float adj = odd ? step : 0.0f;
    #pragma unroll
    for (int i = 0; i < 8; ++i) {
      c0[i] = (i == worst) ? (f[i] + adj) : f[i];
    }
  }

  // ---- coset 1: closest point of D8 to (x - 1/2), then + 1/2 ----
  {
    float f[8], d[8];
    float sum = 0.0f;
    float best = -1.0f, dworst = 0.0f;
    int worst = 0;
    #pragma unroll
    for (int i = 0; i < 8; ++i) {
      float y = xr[i] - 0.5f;
      f[i] = rintf(y);
      d[i] = y - f[i];
      float ad = fabsf(d[i]);
      if (ad > best) { best = ad; worst = i; dworst = d[i]; }
      sum += f[i];
    }
    int odd = ((int)sum) & 1;
    float step = (dworst >= 0.0f) ? 1.0f : -1.0f;
    float adj = odd ? step : 0.0f;
    #pragma unroll
    for (int i = 0; i < 8; ++i) {
      float fi = (i == worst) ? (f[i] + adj) : f[i];
      c1[i] = fi + 0.5f;   // exact: integer + 0.5 in fp32
    }
  }

  // ---- squared distances, numpy pairwise order, no FMA ----
  float q0[8], q1[8];
  #pragma unroll
  for (int i = 0; i < 8; ++i) {
    float r0 = xr[i] - c0[i];
    q0[i] = r0 * r0;
    float r1 = xr[i] - c1[i];
    q1[i] = r1 * r1;
  }
  float d0 = ((q0[0] + q0[1]) + (q0[2] + q0[3])) + ((q0[4] + q0[5]) + (q0[6] + q0[7]));
  float d1 = ((q1[0] + q1[1]) + (q1[2] + q1[3])) + ((q1[4] + q1[5]) + (q1[6] + q1[7]));

  bool pick0 = (d0 <= d1);
  #pragma unroll
  for (int i = 0; i < 8; ++i) {
    o[i] = pick0 ? c0[i] : c1[i];
  }
}

__global__ __launch_bounds__(256) void e8_decode_kernel(
    const float* __restrict__ x, float* __restrict__ out, int npairs, int nrows) {
  int stride = gridDim.x * blockDim.x;
  for (int p = blockIdx.x * blockDim.x + threadIdx.x; p < npairs; p += stride) {
    const float4* xv = reinterpret_cast<const float4*>(x) + (size_t)p * 4;
    float4 v0 = xv[0];
    float4 v1 = xv[1];
    float4 v2 = xv[2];
    float4 v3 = xv[3];

    float ra[8] = {v0.x, v0.y, v0.z, v0.w, v1.x, v1.y, v1.z, v1.w};
    float rb[8] = {v2.x, v2.y, v2.z, v2.w, v3.x, v3.y, v3.z, v3.w};
    float oa[8], ob[8];
    e8_decode_row(ra, oa);
    e8_decode_row(rb, ob);

    float4* ov = reinterpret_cast<float4*>(out) + (size_t)p * 4;
    ov[0] = make_float4(oa[0], oa[1], oa[2], oa[3]);
    ov[1] = make_float4(oa[4], oa[5], oa[6], oa[7]);
    ov[2] = make_float4(ob[0], ob[1], ob[2], ob[3]);
    ov[3] = make_float4(ob[4], ob[5], ob[6], ob[7]);
  }

  // tail: odd final row (not hit for 4M rows, kept for generality)
  if (nrows & 1) {
    int last = nrows - 1;
    if (blockIdx.x == 0 && threadIdx.x == 0) {
      const float4* xv = reinterpret_cast<const float4*>(x) + (size_t)last * 2;
      float4 a = xv[0];
      float4 b = xv[1];
      float r[8] = {a.x, a.y, a.z, a.w, b.x, b.y, b.z, b.w};
      float o[8];
      e8_decode_row(r, o);
      float4* ov = reinterpret_cast<float4*>(out) + (size_t)last * 2;
      ov[0] = make_float4(o[0], o[1], o[2], o[3]);
      ov[1] = make_float4(o[4], o[5], o[6], o[7]);
    }
  }
}

extern "C" void kernel_launch(void* const* d_in, const int* in_sizes, int n_in,
                              void* d_out, int out_size, void* d_ws, size_t ws_size,
                              hipStream_t stream) {
  const float* x = (const float*)d_in[0];
  float* out = (float*)d_out;
  int nrows = in_sizes[0] / 8;
  int npairs = nrows / 2;
  int block = 256;
  int grid = (npairs + block - 1) / block;
  if (grid > 2048) grid = 2048;   // 8192 waves = full residency; grid-stride covers rest
  e8_decode_kernel<<<grid, block, 0, stream>>>(x, out, npairs, nrows);
}

// Round 8
// 226.644 us; speedup vs baseline: 1.1578x; 1.0409x over previous
//
#include <hip/hip_runtime.h>

// E8 lattice closest-point decode — DENSE layout, one 16B chunk per thread.
//
// Round-7 lesson: 64B/thread (2 rows) put each load instr's 64 lanes at
// stride 64B = 1 lane per cache line, 64 lines/instr, re-touched 4x ->
// 2.2 TB/s. Dense 16B/lane (this kernel) gives 16 lines/instr with 4-lane
// merges — the pattern the 6.3 TB/s copy kernels use.
//
// Scheme: lane pair (2j, 2j+1) holds row j's two halves. 4x shfl_xor(1)
// assembles the full row in both lanes. Each lane decodes ONE coset with
// UNIFORM code: c = closestD8(x - h) + h, h = 0.5*(lane&1)  (even lane ->
// D8, odd lane -> D8+1/2; identical instruction stream, no divergence).
// Exchange distances (1 shfl), both lanes compute the pick identically,
// exchange the winner-half (4 shfl), store own 16B chunk densely.
//
// Bit-exactness vs the JAX/numpy reference:
//  - jnp.round == round-half-to-even == rintf (v_rndne_f32)
//  - jnp.argmax: first index of max -> forward scan, strict '>'
//  - distance sums use numpy's pairwise tree; FMA contraction disabled
//  - coset-1 residual is x - (f + 0.5): c is formed first, then x - c
//  - both lanes compare the SAME two fp32 scalars d0,d1 -> identical pick

__global__ __launch_bounds__(256) void e8_dense_kernel(
    const float* __restrict__ x, float* __restrict__ out, int nchunks) {
  #pragma clang fp contract(off)
  int t = blockIdx.x * blockDim.x + threadIdx.x;
  // All lanes participate in shuffles; only in-range lanes store.
  // nchunks is even, so a lane and its partner are in/out of range together.
  int tc = (t < nchunks) ? t : (nchunks - 1);
  int odd_lane = t & 1;

  const float4 mine4 = reinterpret_cast<const float4*>(x)[tc];
  float m[4] = {mine4.x, mine4.y, mine4.z, mine4.w};
  float th[4];
  #pragma unroll
  for (int k = 0; k < 4; ++k) th[k] = __shfl_xor(m[k], 1, 64);

  // Assemble the full row (8 floats) in both lanes of the pair.
  float xr[8];
  #pragma unroll
  for (int k = 0; k < 4; ++k) {
    xr[k]     = odd_lane ? th[k] : m[k];
    xr[k + 4] = odd_lane ? m[k]  : th[k];
  }

  // ---- decode own coset: c = closestD8(xr - h) + h ----
  float h = odd_lane ? 0.5f : 0.0f;
  float f[8];
  float sum = 0.0f;
  float best = -1.0f, dworst = 0.0f;
  int worst = 0;
  #pragma unroll
  for (int i = 0; i < 8; ++i) {
    float y = xr[i] - h;
    f[i] = rintf(y);
    float di = y - f[i];
    float ad = fabsf(di);
    if (ad > best) { best = ad; worst = i; dworst = di; }
    sum += f[i];
  }
  int oddpar = ((int)sum) & 1;
  float step = (dworst >= 0.0f) ? 1.0f : -1.0f;
  float adj = oddpar ? step : 0.0f;
  float c[8];
  #pragma unroll
  for (int i = 0; i < 8; ++i) {
    float fi = (i == worst) ? (f[i] + adj) : f[i];
    c[i] = fi + h;              // h=0: exact; h=0.5: integer+0.5 exact
  }

  // ---- squared distance, numpy pairwise tree, residual x - c ----
  float q[8];
  #pragma unroll
  for (int i = 0; i < 8; ++i) {
    float r = xr[i] - c[i];
    q[i] = r * r;
  }
  float dmine = ((q[0] + q[1]) + (q[2] + q[3])) + ((q[4] + q[5]) + (q[6] + q[7]));
  float dtheirs = __shfl_xor(dmine, 1, 64);
  float d0 = odd_lane ? dtheirs : dmine;   // coset-0 distance
  float d1 = odd_lane ? dmine   : dtheirs; // coset-1 distance
  bool pick0 = (d0 <= d1);                 // ties -> coset 0, as reference
  bool pick_own = odd_lane ? !pick0 : pick0;

  // ---- exchange the half the partner needs ----
  // even sends c[4..7] (odd's chunk range), odd sends c[0..3] (even's range)
  float send[4], recv[4];
  #pragma unroll
  for (int k = 0; k < 4; ++k) send[k] = odd_lane ? c[k] : c[k + 4];
  #pragma unroll
  for (int k = 0; k < 4; ++k) recv[k] = __shfl_xor(send[k], 1, 64);

  float ownh[4];
  #pragma unroll
  for (int k = 0; k < 4; ++k) ownh[k] = odd_lane ? c[k + 4] : c[k];

  float4 o;
  o.x = pick_own ? ownh[0] : recv[0];
  o.y = pick_own ? ownh[1] : recv[1];
  o.z = pick_own ? ownh[2] : recv[2];
  o.w = pick_own ? ownh[3] : recv[3];

  if (t < nchunks) {
    reinterpret_cast<float4*>(out)[t] = o;
  }
}

extern "C" void kernel_launch(void* const* d_in, const int* in_sizes, int n_in,
                              void* d_out, int out_size, void* d_ws, size_t ws_size,
                              hipStream_t stream) {
  const float* x = (const float*)d_in[0];
  float* out = (float*)d_out;
  int nchunks = in_sizes[0] / 4;   // one float4 chunk per thread (half a row)
  int block = 256;
  int grid = (nchunks + block - 1) / block;
  e8_dense_kernel<<<grid, block, 0, stream>>>(x, out, nchunks);
}

// Round 9
// 221.186 us; speedup vs baseline: 1.1864x; 1.0247x over previous
//
#include <hip/hip_runtime.h>

// E8 lattice closest-point decode — r2's proven decode (absmax 0.0), with:
//  - grid-stride, 2048 blocks x 256 (32 waves/CU), ONE row (32B) per iter
//  - software prefetch: next iteration's 2x float4 issued before decode
//  - NONTEMPORAL LOADS only (read-once input; no partial-line hazard on
//    loads; keeps L2/L3 room for the store stream + harness drain).
//    Stores are PLAIN: r5 showed nt stores cause 1.5x WRITE_SIZE.
//
// Bit-exactness vs the JAX/numpy reference:
//  - jnp.round == round-half-to-even == rintf (v_rndne_f32)
//  - jnp.argmax: first index of max -> forward scan, strict '>'
//  - distance sums use numpy's pairwise tree; FMA contraction disabled
//  - coset-1 residual is x - (f + 0.5): c formed first, then x - c

typedef float f32x4 __attribute__((ext_vector_type(4)));

__device__ __forceinline__ void e8_decode_row(const float xr[8], float o[8]) {
  #pragma clang fp contract(off)
  float c0[8], c1[8];

  // ---- coset 0: closest point of D8 to x ----
  {
    float f[8], d[8];
    float sum = 0.0f;
    float best = -1.0f, dworst = 0.0f;
    int worst = 0;
    #pragma unroll
    for (int i = 0; i < 8; ++i) {
      f[i] = rintf(xr[i]);
      d[i] = xr[i] - f[i];
      float ad = fabsf(d[i]);
      if (ad > best) { best = ad; worst = i; dworst = d[i]; }
      sum += f[i];
    }
    int odd = ((int)sum) & 1;
    float step = (dworst >= 0.0f) ? 1.0f : -1.0f;
    float adj = odd ? step : 0.0f;
    #pragma unroll
    for (int i = 0; i < 8; ++i) {
      c0[i] = (i == worst) ? (f[i] + adj) : f[i];
    }
  }

  // ---- coset 1: closest point of D8 to (x - 1/2), then + 1/2 ----
  {
    float f[8], d[8];
    float sum = 0.0f;
    float best = -1.0f, dworst = 0.0f;
    int worst = 0;
    #pragma unroll
    for (int i = 0; i < 8; ++i) {
      float y = xr[i] - 0.5f;
      f[i] = rintf(y);
      d[i] = y - f[i];
      float ad = fabsf(d[i]);
      if (ad > best) { best = ad; worst = i; dworst = d[i]; }
      sum += f[i];
    }
    int odd = ((int)sum) & 1;
    float step = (dworst >= 0.0f) ? 1.0f : -1.0f;
    float adj = odd ? step : 0.0f;
    #pragma unroll
    for (int i = 0; i < 8; ++i) {
      float fi = (i == worst) ? (f[i] + adj) : f[i];
      c1[i] = fi + 0.5f;   // exact: integer + 0.5 in fp32
    }
  }

  // ---- squared distances, numpy pairwise order, no FMA ----
  float q0[8], q1[8];
  #pragma unroll
  for (int i = 0; i < 8; ++i) {
    float r0 = xr[i] - c0[i];
    q0[i] = r0 * r0;
    float r1 = xr[i] - c1[i];
    q1[i] = r1 * r1;
  }
  float d0 = ((q0[0] + q0[1]) + (q0[2] + q0[3])) + ((q0[4] + q0[5]) + (q0[6] + q0[7]));
  float d1 = ((q1[0] + q1[1]) + (q1[2] + q1[3])) + ((q1[4] + q1[5]) + (q1[6] + q1[7]));

  bool pick0 = (d0 <= d1);
  #pragma unroll
  for (int i = 0; i < 8; ++i) {
    o[i] = pick0 ? c0[i] : c1[i];
  }
}

__global__ __launch_bounds__(256) void e8_decode_kernel(
    const float* __restrict__ x, float* __restrict__ out, int nrows) {
  const int stride = gridDim.x * blockDim.x;
  int row = blockIdx.x * blockDim.x + threadIdx.x;
  if (row >= nrows) return;

  const f32x4* __restrict__ xv = reinterpret_cast<const f32x4*>(x);
  float4* __restrict__ ov = reinterpret_cast<float4*>(out);

  // prologue load
  f32x4 a = __builtin_nontemporal_load(xv + (size_t)row * 2);
  f32x4 b = __builtin_nontemporal_load(xv + (size_t)row * 2 + 1);

  while (true) {
    // issue NEXT iteration's loads before this iteration's compute
    int nrow = row + stride;
    bool more = nrow < nrows;
    f32x4 an, bn;
    if (more) {
      an = __builtin_nontemporal_load(xv + (size_t)nrow * 2);
      bn = __builtin_nontemporal_load(xv + (size_t)nrow * 2 + 1);
    }

    float xr[8] = {a.x, a.y, a.z, a.w, b.x, b.y, b.z, b.w};
    float o[8];
    e8_decode_row(xr, o);

    ov[(size_t)row * 2]     = make_float4(o[0], o[1], o[2], o[3]);
    ov[(size_t)row * 2 + 1] = make_float4(o[4], o[5], o[6], o[7]);

    if (!more) break;
    row = nrow;
    a = an;
    b = bn;
  }
}

extern "C" void kernel_launch(void* const* d_in, const int* in_sizes, int n_in,
                              void* d_out, int out_size, void* d_ws, size_t ws_size,
                              hipStream_t stream) {
  const float* x = (const float*)d_in[0];
  float* out = (float*)d_out;
  int nrows = in_sizes[0] / 8;
  int block = 256;
  int grid = (nrows + block - 1) / block;
  if (grid > 2048) grid = 2048;   // 8192 waves = full 32-wave/CU residency
  e8_decode_kernel<<<grid, block, 0, stream>>>(x, out, nrows);
}